// Round 7
// baseline (659.249 us; speedup 1.0000x reference)
//
#include <hip/hip_runtime.h>
#include <hip/hip_bf16.h>

// Problem constants
#define HEADS 8
#define CH    64
#define HC    512   // HEADS*CH
#define NGR   64
#define NEGS  0.2f
#define BNB   60    // bn_stats blocks

__device__ __forceinline__ float lrelu(float v) {
    return (v > 0.f) ? v : NEGS * v;
}

// bf16 (as ushort) -> fp32
__device__ __forceinline__ float bf2f_lo(unsigned u) { return __uint_as_float(u << 16); }
__device__ __forceinline__ float bf2f_hi(unsigned u) { return __uint_as_float(u & 0xffff0000u); }

// ---------------------------------------------------------------------------
// BN stats stage 1: per-block partial sum/sumsq over 16 features, NO atomics.
__global__ void bn_stats_kernel(const float* __restrict__ x, float* __restrict__ partials,
                                int N, int chunk) {
    int n0 = blockIdx.x * chunk;
    int n1 = min(n0 + chunk, N);
    float s[16], q[16];
#pragma unroll
    for (int i = 0; i < 16; i++) { s[i] = 0.f; q[i] = 0.f; }
    for (int r = n0 + threadIdx.x; r < n1; r += 256) {
        const float4* xr = (const float4*)(x + (size_t)r * 16);
#pragma unroll
        for (int i = 0; i < 4; i++) {
            float4 v = xr[i];
            s[4*i+0] += v.x; q[4*i+0] += v.x * v.x;
            s[4*i+1] += v.y; q[4*i+1] += v.y * v.y;
            s[4*i+2] += v.z; q[4*i+2] += v.z * v.z;
            s[4*i+3] += v.w; q[4*i+3] += v.w * v.w;
        }
    }
#pragma unroll
    for (int k = 0; k < 16; k++) {
#pragma unroll
        for (int off = 32; off; off >>= 1) {
            s[k] += __shfl_down(s[k], off);
            q[k] += __shfl_down(q[k], off);
        }
    }
    __shared__ float lds[4][32];
    int lane = threadIdx.x & 63, wid = threadIdx.x >> 6;
    if (lane == 0) {
#pragma unroll
        for (int k = 0; k < 16; k++) { lds[wid][k] = s[k]; lds[wid][16 + k] = q[k]; }
    }
    __syncthreads();
    int t = threadIdx.x;
    if (t < 32) {
        float v = lds[0][t] + lds[1][t] + lds[2][t] + lds[3][t];
        partials[(size_t)blockIdx.x * 32 + t] = v;
    }
}

// BN stage 2: stats[32..47]=scale, stats[48..63]=shift.
__global__ void bn_finalize_kernel(const float* __restrict__ partials, float* __restrict__ stats,
                                   const float* __restrict__ gamma,
                                   const float* __restrict__ beta, int N, int nblk) {
    __shared__ float sums[32];
    int t = threadIdx.x;
    if (t < 32) {
        float v = 0.f;
        for (int b = 0; b < nblk; b++) v += partials[(size_t)b * 32 + t];
        sums[t] = v;
    }
    __syncthreads();
    if (t < 16) {
        float invn = 1.f / (float)N;
        float mean = sums[t] * invn;
        float var  = sums[16 + t] * invn - mean * mean;
        float sc   = gamma[t] * rsqrtf(var + 1e-5f);
        stats[32 + t] = sc;
        stats[48 + t] = beta[t] - mean * sc;
    }
}

// ---------------------------------------------------------------------------
// u/v precompute for all 3 layers: u[k,h] = sum_c W[k, h*64+c] * a_src[h,c]
// (asv[n,h] = x_n . u[:,h] exactly — replaces the 30MB-read asad kernels).
// uv layout: [0]=u1(16x8) [128]=v1 [256]=u2(64x8) [768]=v2 [1280]=u3 [1792]=v3
__global__ void uv_kernel(const float* __restrict__ W1, const float* __restrict__ a1s,
                          const float* __restrict__ a1d,
                          const float* __restrict__ W2, const float* __restrict__ a2s,
                          const float* __restrict__ a2d,
                          const float* __restrict__ W3, const float* __restrict__ a3s,
                          const float* __restrict__ a3d,
                          float* __restrict__ uv) {
    int layer = blockIdx.x;
    const float* W  = (layer == 0) ? W1  : (layer == 1) ? W2  : W3;
    const float* as = (layer == 0) ? a1s : (layer == 1) ? a2s : a3s;
    const float* ad = (layer == 0) ? a1d : (layer == 1) ? a2d : a3d;
    int K = (layer == 0) ? 16 : 64;
    int uofs = (layer == 0) ? 0 : (layer == 1) ? 256 : 1280;
    int t = threadIdx.x;
    if (t >= K * 8) return;
    int k = t >> 3, h = t & 7;
    const float* wr = W + (size_t)k * HC + h * CH;
    const float* sr = as + h * CH;
    const float* dr = ad + h * CH;
    float su = 0.f, sv = 0.f;
#pragma unroll 8
    for (int c = 0; c < CH; c++) { su += wr[c] * sr[c]; sv += wr[c] * dr[c]; }
    uv[uofs + k * 8 + h] = su;
    uv[uofs + K * 8 + k * 8 + h] = sv;
}

// ---------------------------------------------------------------------------
// CSR build over dst (edges + self loops). E2 = E + N.
__global__ void count_kernel(const int* __restrict__ ei, int E, int E2,
                             int* __restrict__ counts) {
    int i = blockIdx.x * blockDim.x + threadIdx.x;
    if (i >= E2) return;
    int dst = (i < E) ? ei[E + i] : (i - E);
    atomicAdd(counts + dst, 1);
}

// Single-block scan, 4 elems/thread (int4).
__global__ void scan_kernel(const int* __restrict__ counts, int* __restrict__ rowptr,
                            int* __restrict__ cursor, int N) {
    __shared__ int wsum[16];
    __shared__ int base_s;
    int t = threadIdx.x;
    int lane = t & 63, wid = t >> 6;
    if (t == 0) base_s = 0;
    __syncthreads();
    for (int start = 0; start < N; start += 4096) {
        int i0 = start + t * 4;
        int e0 = 0, e1 = 0, e2 = 0, e3 = 0;
        if (i0 + 3 < N) {
            const int4 c4 = *(const int4*)(counts + i0);
            e0 = c4.x; e1 = c4.y; e2 = c4.z; e3 = c4.w;
        } else {
            if (i0 + 0 < N) e0 = counts[i0 + 0];
            if (i0 + 1 < N) e1 = counts[i0 + 1];
            if (i0 + 2 < N) e2 = counts[i0 + 2];
            if (i0 + 3 < N) e3 = counts[i0 + 3];
        }
        int tot = e0 + e1 + e2 + e3;
        int v = tot;
#pragma unroll
        for (int off = 1; off < 64; off <<= 1) {
            int u = __shfl_up(v, off);
            if (lane >= off) v += u;
        }
        if (lane == 63) wsum[wid] = v;
        __syncthreads();
        if (t < 16) {
            int w = wsum[t];
#pragma unroll
            for (int off = 1; off < 16; off <<= 1) {
                int u = __shfl_up(w, off);
                if (t >= off) w += u;
            }
            wsum[t] = w;
        }
        __syncthreads();
        int excl = base_s + (v - tot) + (wid ? wsum[wid - 1] : 0);
        int p0 = excl, p1 = p0 + e0, p2 = p1 + e1, p3 = p2 + e2;
        if (i0 + 3 < N) {
            *(int4*)(rowptr + i0) = make_int4(p0, p1, p2, p3);
            *(int4*)(cursor + i0) = make_int4(p0, p1, p2, p3);
        } else {
            if (i0 + 0 < N) { rowptr[i0 + 0] = p0; cursor[i0 + 0] = p0; }
            if (i0 + 1 < N) { rowptr[i0 + 1] = p1; cursor[i0 + 1] = p1; }
            if (i0 + 2 < N) { rowptr[i0 + 2] = p2; cursor[i0 + 2] = p2; }
            if (i0 + 3 < N) { rowptr[i0 + 3] = p3; cursor[i0 + 3] = p3; }
        }
        __syncthreads();
        if (t == 0) base_s += wsum[15];
        __syncthreads();
    }
    if (t == 0) rowptr[N] = base_s;
}

// Scatter edge (src,dst) into CSR order.
__global__ void scatter_kernel(const int* __restrict__ ei, int E, int E2,
                               int* __restrict__ cursor,
                               int* __restrict__ src_csr, int* __restrict__ dst_csr) {
    int i = blockIdx.x * blockDim.x + threadIdx.x;
    if (i >= E2) return;
    int src, dst;
    if (i < E) { src = ei[i]; dst = ei[E + i]; }
    else       { src = i - E; dst = src; }
    int pos = atomicAdd(cursor + dst, 1);
    src_csr[pos] = src;
    dst_csr[pos] = dst;
}

// ---------------------------------------------------------------------------
// GEMM: h[N,512](bf16) = xin[N,K](fp32) @ W[K,512]; optional fused BN (layer 1).
// Fused asv/adv epilogue: asv[n,h] = xs_row . u[:,h] (exact K-dot from LDS).
// BM=16: 1875 blocks -> ~7.3 blocks/CU for latency hiding.
template <int K>
__global__ void gemm_kernel(const float* __restrict__ xin, const float* __restrict__ W,
                            __hip_bfloat16* __restrict__ hout, int N,
                            const float* __restrict__ scale, const float* __restrict__ shift,
                            const float* __restrict__ u, const float* __restrict__ v,
                            float* __restrict__ asv, float* __restrict__ adv) {
    const int BM = 16;
    __shared__ float xs[BM * K];
    int row0 = blockIdx.x * BM;
    int t = threadIdx.x;
    for (int idx = t; idx < BM * K; idx += 256) {
        int r = row0 + idx / K;
        int f = idx & (K - 1);
        float vv = (r < N) ? xin[(size_t)r * K + f] : 0.f;
        if (scale) vv = vv * scale[f] + shift[f];
        xs[idx] = vv;
    }
    __syncthreads();
    int c0 = t, c1 = t + 256;
    float acc0[BM], acc1[BM];
#pragma unroll
    for (int r = 0; r < BM; r++) { acc0[r] = 0.f; acc1[r] = 0.f; }
    for (int k = 0; k < K; k++) {
        float w0 = W[(size_t)k * HC + c0];
        float w1 = W[(size_t)k * HC + c1];
#pragma unroll
        for (int r = 0; r < BM; r++) {
            float a = xs[r * K + k];
            acc0[r] += a * w0;
            acc1[r] += a * w1;
        }
    }
#pragma unroll
    for (int r = 0; r < BM; r++) {
        int rr = row0 + r;
        if (rr < N) {
            hout[(size_t)rr * HC + c0] = __float2bfloat16(acc0[r]);
            hout[(size_t)rr * HC + c1] = __float2bfloat16(acc1[r]);
        }
    }
    // asv/adv epilogue: 128 threads, each one (row, head) K-dot from LDS.
    if (t < BM * 8) {
        int r = t >> 3, hh = t & 7;
        int rr = row0 + r;
        if (rr < N) {
            float su = 0.f, sv = 0.f;
            for (int k = 0; k < K; k++) {
                float xv = xs[r * K + k];
                su += xv * u[k * 8 + hh];
                sv += xv * v[k * 8 + hh];
            }
            asv[(size_t)rr * 8 + hh] = su;
            adv[(size_t)rr * 8 + hh] = sv;
        }
    }
}

// ---------------------------------------------------------------------------
// Unnormalized attention weights in CSR order: alpha[j][h] = exp(lrelu(...)).
__global__ void alpha_kernel(const int* __restrict__ src_csr, const int* __restrict__ dst_csr,
                             const float* __restrict__ asv, const float* __restrict__ adv,
                             float* __restrict__ alpha_csr, int E2) {
    int tid = blockIdx.x * blockDim.x + threadIdx.x;
    if (tid >= E2 * 8) return;
    int j = tid >> 3, h = tid & 7;
    int s = src_csr[j], d = dst_csr[j];
    float e = lrelu(asv[(size_t)s * 8 + h] + adv[(size_t)d * 8 + h]);
    alpha_csr[tid] = __expf(e);
}

// ---------------------------------------------------------------------------
// Aggregation: one WAVE per dst node, PURE gather+FMA loop, 4-edge unroll.
__global__ void agg_kernel(const int* __restrict__ rp, const int* __restrict__ src_csr,
                           const float* __restrict__ alpha_csr,
                           const ushort* __restrict__ hbuf, const float* __restrict__ bias,
                           float* __restrict__ xout, int N, int dorelu) {
    int gw = (blockIdx.x * blockDim.x + threadIdx.x) >> 6;  // node id
    int lane = threadIdx.x & 63;
    if (gw >= N) return;
    int head = lane >> 3;
    size_t lofs = 8 * (size_t)lane;
    int jb = rp[gw], je = rp[gw + 1];
    float acc[8];
#pragma unroll
    for (int r = 0; r < 8; r++) acc[r] = 0.f;
    float den = 0.f;
    int j = jb;
    for (; j + 4 <= je; j += 4) {
        int s0 = src_csr[j],     s1 = src_csr[j + 1];
        int s2 = src_csr[j + 2], s3 = src_csr[j + 3];
        float w0 = alpha_csr[(size_t)j * 8 + head];
        float w1 = alpha_csr[(size_t)(j + 1) * 8 + head];
        float w2 = alpha_csr[(size_t)(j + 2) * 8 + head];
        float w3 = alpha_csr[(size_t)(j + 3) * 8 + head];
        uint4 p0 = *(const uint4*)(hbuf + (size_t)s0 * HC + lofs);
        uint4 p1 = *(const uint4*)(hbuf + (size_t)s1 * HC + lofs);
        uint4 p2 = *(const uint4*)(hbuf + (size_t)s2 * HC + lofs);
        uint4 p3 = *(const uint4*)(hbuf + (size_t)s3 * HC + lofs);
        den += (w0 + w1) + (w2 + w3);
        acc[0] += w0 * bf2f_lo(p0.x); acc[1] += w0 * bf2f_hi(p0.x);
        acc[2] += w0 * bf2f_lo(p0.y); acc[3] += w0 * bf2f_hi(p0.y);
        acc[4] += w0 * bf2f_lo(p0.z); acc[5] += w0 * bf2f_hi(p0.z);
        acc[6] += w0 * bf2f_lo(p0.w); acc[7] += w0 * bf2f_hi(p0.w);
        acc[0] += w1 * bf2f_lo(p1.x); acc[1] += w1 * bf2f_hi(p1.x);
        acc[2] += w1 * bf2f_lo(p1.y); acc[3] += w1 * bf2f_hi(p1.y);
        acc[4] += w1 * bf2f_lo(p1.z); acc[5] += w1 * bf2f_hi(p1.z);
        acc[6] += w1 * bf2f_lo(p1.w); acc[7] += w1 * bf2f_hi(p1.w);
        acc[0] += w2 * bf2f_lo(p2.x); acc[1] += w2 * bf2f_hi(p2.x);
        acc[2] += w2 * bf2f_lo(p2.y); acc[3] += w2 * bf2f_hi(p2.y);
        acc[4] += w2 * bf2f_lo(p2.z); acc[5] += w2 * bf2f_hi(p2.z);
        acc[6] += w2 * bf2f_lo(p2.w); acc[7] += w2 * bf2f_hi(p2.w);
        acc[0] += w3 * bf2f_lo(p3.x); acc[1] += w3 * bf2f_hi(p3.x);
        acc[2] += w3 * bf2f_lo(p3.y); acc[3] += w3 * bf2f_hi(p3.y);
        acc[4] += w3 * bf2f_lo(p3.z); acc[5] += w3 * bf2f_hi(p3.z);
        acc[6] += w3 * bf2f_lo(p3.w); acc[7] += w3 * bf2f_hi(p3.w);
    }
    for (; j < je; j++) {
        int s0 = src_csr[j];
        float w0 = alpha_csr[(size_t)j * 8 + head];
        uint4 p0 = *(const uint4*)(hbuf + (size_t)s0 * HC + lofs);
        den += w0;
        acc[0] += w0 * bf2f_lo(p0.x); acc[1] += w0 * bf2f_hi(p0.x);
        acc[2] += w0 * bf2f_lo(p0.y); acc[3] += w0 * bf2f_hi(p0.y);
        acc[4] += w0 * bf2f_lo(p0.z); acc[5] += w0 * bf2f_hi(p0.z);
        acc[6] += w0 * bf2f_lo(p0.w); acc[7] += w0 * bf2f_hi(p0.w);
    }
    float inv = 1.f / (den + 1e-16f);
#pragma unroll
    for (int r = 0; r < 8; r++) {
        acc[r] *= inv;
        acc[r] += __shfl_xor(acc[r], 8);
        acc[r] += __shfl_xor(acc[r], 16);
        acc[r] += __shfl_xor(acc[r], 32);
    }
    if (lane < 8) {
        const float4* b4 = (const float4*)(bias + 8 * lane);
        float4 bv0 = b4[0], bv1 = b4[1];
        float4 o0, o1;
        o0.x = acc[0] * 0.125f + bv0.x;
        o0.y = acc[1] * 0.125f + bv0.y;
        o0.z = acc[2] * 0.125f + bv0.z;
        o0.w = acc[3] * 0.125f + bv0.w;
        o1.x = acc[4] * 0.125f + bv1.x;
        o1.y = acc[5] * 0.125f + bv1.y;
        o1.z = acc[6] * 0.125f + bv1.z;
        o1.w = acc[7] * 0.125f + bv1.w;
        if (dorelu) {
            o0.x = fmaxf(o0.x, 0.f); o0.y = fmaxf(o0.y, 0.f);
            o0.z = fmaxf(o0.z, 0.f); o0.w = fmaxf(o0.w, 0.f);
            o1.x = fmaxf(o1.x, 0.f); o1.y = fmaxf(o1.y, 0.f);
            o1.z = fmaxf(o1.z, 0.f); o1.w = fmaxf(o1.w, 0.f);
        }
        float4* op = (float4*)(xout + (size_t)gw * CH + 8 * lane);
        op[0] = o0;
        op[1] = o1;
    }
}

// ---------------------------------------------------------------------------
// Pool: batch sorted -> run-local accumulation, atomic flush per boundary.
__global__ void pool_kernel(const float* __restrict__ x, const int* __restrict__ batch,
                            float* __restrict__ pools, float* __restrict__ pcnt,
                            int N, int chunk) {
    int c  = threadIdx.x & 63;
    int nl = threadIdx.x >> 6;   // 0..3
    int n0 = blockIdx.x * chunk;
    int n1 = min(n0 + chunk, N);
    float acc = 0.f, cnt = 0.f;
    int curg = -1;
    for (int n = n0 + nl; n < n1; n += 4) {
        int g = batch[n];
        if (g != curg) {
            if (curg >= 0) {
                atomicAdd(pools + (size_t)curg * CH + c, acc);
                if (c == 0) atomicAdd(pcnt + curg, cnt);
            }
            curg = g; acc = 0.f; cnt = 0.f;
        }
        acc += x[(size_t)n * CH + c];
        cnt += 1.f;
    }
    if (curg >= 0) {
        atomicAdd(pools + (size_t)curg * CH + c, acc);
        if (c == 0) atomicAdd(pcnt + curg, cnt);
    }
}

__global__ void final_kernel(const float* __restrict__ pools, const float* __restrict__ pcnt,
                             const float* __restrict__ linW, const float* __restrict__ linb,
                             float* __restrict__ out) {
    int t = threadIdx.x;
    if (t >= NGR * 2) return;
    int g = t >> 1, k = t & 1;
    float inv = 1.f / fmaxf(pcnt[g], 1.f);
    float acc = 0.f;
#pragma unroll
    for (int c = 0; c < CH; c++)
        acc += pools[(size_t)g * CH + c] * inv * linW[c * 2 + k];
    out[g * 2 + k] = acc + linb[k];
}

// ---------------------------------------------------------------------------
extern "C" void kernel_launch(void* const* d_in, const int* in_sizes, int n_in,
                              void* d_out, int out_size, void* d_ws, size_t ws_size,
                              hipStream_t stream) {
    const float* x      = (const float*)d_in[0];
    const int*   ei     = (const int*)d_in[1];
    const int*   batch  = (const int*)d_in[3];
    const float* gamma  = (const float*)d_in[4];
    const float* beta   = (const float*)d_in[5];
    const float* W1     = (const float*)d_in[6];
    const float* a1s    = (const float*)d_in[7];
    const float* a1d    = (const float*)d_in[8];
    const float* b1     = (const float*)d_in[9];
    const float* W2     = (const float*)d_in[10];
    const float* a2s    = (const float*)d_in[11];
    const float* a2d    = (const float*)d_in[12];
    const float* b2     = (const float*)d_in[13];
    const float* W3     = (const float*)d_in[14];
    const float* a3s    = (const float*)d_in[15];
    const float* a3d    = (const float*)d_in[16];
    const float* b3     = (const float*)d_in[17];
    const float* linW   = (const float*)d_in[18];
    const float* linb   = (const float*)d_in[19];
    float* out = (float*)d_out;

    const int N  = in_sizes[0] / 16;
    const int E  = in_sizes[1] / 2;
    const int E2 = E + N;

    // Workspace layout (256B aligned slices)
    char* p = (char*)d_ws;
    size_t off = 0;
    auto alloc = [&](size_t bytes) {
        void* r = p + off;
        off += (bytes + 255) & ~(size_t)255;
        return r;
    };
    __hip_bfloat16* hbuf = (__hip_bfloat16*)alloc((size_t)N * HC * 2);
    float* xa        = (float*)alloc((size_t)N * CH * 4);
    float* xb        = (float*)alloc((size_t)N * CH * 4);
    float* asv       = (float*)alloc((size_t)N * HEADS * 4);
    float* adv       = (float*)alloc((size_t)N * HEADS * 4);
    float* alpha_csr = (float*)alloc((size_t)E2 * HEADS * 4);
    float* stats     = (float*)alloc(64 * 4);
    float* partials  = (float*)alloc((size_t)BNB * 32 * 4);
    float* uv        = (float*)alloc(2304 * 4);
    float* pools     = (float*)alloc((size_t)NGR * CH * 4);
    float* pcnt      = (float*)alloc(NGR * 4);
    int*   rowptr    = (int*)alloc((size_t)(N + 1) * 4);
    int*   cursor    = (int*)alloc((size_t)N * 4);
    int*   counts    = (int*)alloc((size_t)N * 4);
    int*   src_csr   = (int*)alloc((size_t)E2 * 4);
    int*   dst_csr   = (int*)alloc((size_t)E2 * 4);
    (void)ws_size;

    const int TB = 256;
    int gE2 = (E2 + TB - 1) / TB;
    int gEH = (E2 * 8 + TB - 1) / TB;
    int gGm = (N + 15) / 16;               // BM=16
    int gWv = (N * 64 + TB - 1) / TB;      // one wave per node
    const int PCHUNK = 256;
    int gPool = (N + PCHUNK - 1) / PCHUNK;
    int bnChunk = (N + BNB - 1) / BNB;

    const ushort* hb = (const ushort*)hbuf;

    // zero-init accumulators
    hipMemsetAsync(counts, 0, (size_t)N * 4, stream);
    hipMemsetAsync(pools, 0, (size_t)NGR * CH * 4, stream);
    hipMemsetAsync(pcnt, 0, NGR * 4, stream);

    // BN statistics (two-stage deterministic reduction) + u/v precompute
    bn_stats_kernel<<<BNB, TB, 0, stream>>>(x, partials, N, bnChunk);
    bn_finalize_kernel<<<1, 64, 0, stream>>>(partials, stats, gamma, beta, N, BNB);
    uv_kernel<<<3, 512, 0, stream>>>(W1, a1s, a1d, W2, a2s, a2d, W3, a3s, a3d, uv);

    // CSR over dst
    count_kernel<<<gE2, TB, 0, stream>>>(ei, E, E2, counts);
    scan_kernel<<<1, 1024, 0, stream>>>(counts, rowptr, cursor, N);
    scatter_kernel<<<gE2, TB, 0, stream>>>(ei, E, E2, cursor, src_csr, dst_csr);

    // ---- Layer 1 (BN fused into GEMM staging; asv/adv fused epilogue) ----
    gemm_kernel<16><<<gGm, TB, 0, stream>>>(x, W1, hbuf, N, stats + 32, stats + 48,
                                            uv + 0, uv + 128, asv, adv);
    alpha_kernel<<<gEH, TB, 0, stream>>>(src_csr, dst_csr, asv, adv, alpha_csr, E2);
    agg_kernel<<<gWv, TB, 0, stream>>>(rowptr, src_csr, alpha_csr, hb, b1, xa, N, 1);

    // ---- Layer 2 ----
    gemm_kernel<64><<<gGm, TB, 0, stream>>>(xa, W2, hbuf, N, nullptr, nullptr,
                                            uv + 256, uv + 768, asv, adv);
    alpha_kernel<<<gEH, TB, 0, stream>>>(src_csr, dst_csr, asv, adv, alpha_csr, E2);
    agg_kernel<<<gWv, TB, 0, stream>>>(rowptr, src_csr, alpha_csr, hb, b2, xb, N, 1);

    // ---- Layer 3 ----
    gemm_kernel<64><<<gGm, TB, 0, stream>>>(xb, W3, hbuf, N, nullptr, nullptr,
                                            uv + 1280, uv + 1792, asv, adv);
    alpha_kernel<<<gEH, TB, 0, stream>>>(src_csr, dst_csr, asv, adv, alpha_csr, E2);
    agg_kernel<<<gWv, TB, 0, stream>>>(rowptr, src_csr, alpha_csr, hb, b3, xa, N, 0);

    // ---- Pool + final linear ----
    pool_kernel<<<gPool, TB, 0, stream>>>(xa, batch, pools, pcnt, N, PCHUNK);
    final_kernel<<<1, 128, 0, stream>>>(pools, pcnt, linW, linb, out);
}

// Round 8
// 562.829 us; speedup vs baseline: 1.1713x; 1.1713x over previous
//
#include <hip/hip_runtime.h>
#include <hip/hip_bf16.h>

// Problem constants
#define HEADS 8
#define CH    64
#define HC    512   // HEADS*CH
#define NGR   64
#define NEGS  0.2f
#define BNB   60    // bn_stats blocks

__device__ __forceinline__ float lrelu(float v) {
    return (v > 0.f) ? v : NEGS * v;
}

// bf16 (as ushort) -> fp32
__device__ __forceinline__ float bf2f_lo(unsigned u) { return __uint_as_float(u << 16); }
__device__ __forceinline__ float bf2f_hi(unsigned u) { return __uint_as_float(u & 0xffff0000u); }

// fp32 -> bf16 bits, round-to-nearest-even (finite inputs)
__device__ __forceinline__ unsigned bf16bits(float f) {
    unsigned u = __float_as_uint(f);
    return (u + 0x7fffu + ((u >> 16) & 1u)) >> 16;
}
__device__ __forceinline__ unsigned packbf2(float a, float b) {
    return bf16bits(a) | (bf16bits(b) << 16);
}

// ---------------------------------------------------------------------------
// BN stats stage 1: per-block partial sum/sumsq over 16 features, NO atomics.
__global__ void bn_stats_kernel(const float* __restrict__ x, float* __restrict__ partials,
                                int N, int chunk) {
    int n0 = blockIdx.x * chunk;
    int n1 = min(n0 + chunk, N);
    float s[16], q[16];
#pragma unroll
    for (int i = 0; i < 16; i++) { s[i] = 0.f; q[i] = 0.f; }
    for (int r = n0 + threadIdx.x; r < n1; r += 256) {
        const float4* xr = (const float4*)(x + (size_t)r * 16);
#pragma unroll
        for (int i = 0; i < 4; i++) {
            float4 v = xr[i];
            s[4*i+0] += v.x; q[4*i+0] += v.x * v.x;
            s[4*i+1] += v.y; q[4*i+1] += v.y * v.y;
            s[4*i+2] += v.z; q[4*i+2] += v.z * v.z;
            s[4*i+3] += v.w; q[4*i+3] += v.w * v.w;
        }
    }
#pragma unroll
    for (int k = 0; k < 16; k++) {
#pragma unroll
        for (int off = 32; off; off >>= 1) {
            s[k] += __shfl_down(s[k], off);
            q[k] += __shfl_down(q[k], off);
        }
    }
    __shared__ float lds[4][32];
    int lane = threadIdx.x & 63, wid = threadIdx.x >> 6;
    if (lane == 0) {
#pragma unroll
        for (int k = 0; k < 16; k++) { lds[wid][k] = s[k]; lds[wid][16 + k] = q[k]; }
    }
    __syncthreads();
    int t = threadIdx.x;
    if (t < 32) {
        float v = lds[0][t] + lds[1][t] + lds[2][t] + lds[3][t];
        partials[(size_t)blockIdx.x * 32 + t] = v;
    }
}

// BN stage 2: stats[32..47]=scale, stats[48..63]=shift.
__global__ void bn_finalize_kernel(const float* __restrict__ partials, float* __restrict__ stats,
                                   const float* __restrict__ gamma,
                                   const float* __restrict__ beta, int N, int nblk) {
    __shared__ float sums[32];
    int t = threadIdx.x;
    if (t < 32) {
        float v = 0.f;
        for (int b = 0; b < nblk; b++) v += partials[(size_t)b * 32 + t];
        sums[t] = v;
    }
    __syncthreads();
    if (t < 16) {
        float invn = 1.f / (float)N;
        float mean = sums[t] * invn;
        float var  = sums[16 + t] * invn - mean * mean;
        float sc   = gamma[t] * rsqrtf(var + 1e-5f);
        stats[32 + t] = sc;
        stats[48 + t] = beta[t] - mean * sc;
    }
}

// ---------------------------------------------------------------------------
// u/v precompute: u[k,h] = sum_c W[k, h*64+c] * a_src[h,c]  (asv = x.u exactly)
// uv layout: [0]=u1(16x8) [128]=v1 [256]=u2(64x8) [768]=v2 [1280]=u3 [1792]=v3
__global__ void uv_kernel(const float* __restrict__ W1, const float* __restrict__ a1s,
                          const float* __restrict__ a1d,
                          const float* __restrict__ W2, const float* __restrict__ a2s,
                          const float* __restrict__ a2d,
                          const float* __restrict__ W3, const float* __restrict__ a3s,
                          const float* __restrict__ a3d,
                          float* __restrict__ uv) {
    int layer = blockIdx.x;
    const float* W  = (layer == 0) ? W1  : (layer == 1) ? W2  : W3;
    const float* as = (layer == 0) ? a1s : (layer == 1) ? a2s : a3s;
    const float* ad = (layer == 0) ? a1d : (layer == 1) ? a2d : a3d;
    int K = (layer == 0) ? 16 : 64;
    int uofs = (layer == 0) ? 0 : (layer == 1) ? 256 : 1280;
    int t = threadIdx.x;
    if (t >= K * 8) return;
    int k = t >> 3, h = t & 7;
    const float* wr = W + (size_t)k * HC + h * CH;
    const float* sr = as + h * CH;
    const float* dr = ad + h * CH;
    float su = 0.f, sv = 0.f;
#pragma unroll 8
    for (int c = 0; c < CH; c++) { su += wr[c] * sr[c]; sv += wr[c] * dr[c]; }
    uv[uofs + k * 8 + h] = su;
    uv[uofs + K * 8 + k * 8 + h] = sv;
}

// ---------------------------------------------------------------------------
// CSR build over dst (edges + self loops). E2 = E + N.
__global__ void count_kernel(const int* __restrict__ ei, int E, int E2,
                             int* __restrict__ counts) {
    int i = blockIdx.x * blockDim.x + threadIdx.x;
    if (i >= E2) return;
    int dst = (i < E) ? ei[E + i] : (i - E);
    atomicAdd(counts + dst, 1);
}

// Single-block scan, 4 elems/thread (int4).
__global__ void scan_kernel(const int* __restrict__ counts, int* __restrict__ rowptr,
                            int* __restrict__ cursor, int N) {
    __shared__ int wsum[16];
    __shared__ int base_s;
    int t = threadIdx.x;
    int lane = t & 63, wid = t >> 6;
    if (t == 0) base_s = 0;
    __syncthreads();
    for (int start = 0; start < N; start += 4096) {
        int i0 = start + t * 4;
        int e0 = 0, e1 = 0, e2 = 0, e3 = 0;
        if (i0 + 3 < N) {
            const int4 c4 = *(const int4*)(counts + i0);
            e0 = c4.x; e1 = c4.y; e2 = c4.z; e3 = c4.w;
        } else {
            if (i0 + 0 < N) e0 = counts[i0 + 0];
            if (i0 + 1 < N) e1 = counts[i0 + 1];
            if (i0 + 2 < N) e2 = counts[i0 + 2];
            if (i0 + 3 < N) e3 = counts[i0 + 3];
        }
        int tot = e0 + e1 + e2 + e3;
        int v = tot;
#pragma unroll
        for (int off = 1; off < 64; off <<= 1) {
            int u = __shfl_up(v, off);
            if (lane >= off) v += u;
        }
        if (lane == 63) wsum[wid] = v;
        __syncthreads();
        if (t < 16) {
            int w = wsum[t];
#pragma unroll
            for (int off = 1; off < 16; off <<= 1) {
                int u = __shfl_up(w, off);
                if (t >= off) w += u;
            }
            wsum[t] = w;
        }
        __syncthreads();
        int excl = base_s + (v - tot) + (wid ? wsum[wid - 1] : 0);
        int p0 = excl, p1 = p0 + e0, p2 = p1 + e1, p3 = p2 + e2;
        if (i0 + 3 < N) {
            *(int4*)(rowptr + i0) = make_int4(p0, p1, p2, p3);
            *(int4*)(cursor + i0) = make_int4(p0, p1, p2, p3);
        } else {
            if (i0 + 0 < N) { rowptr[i0 + 0] = p0; cursor[i0 + 0] = p0; }
            if (i0 + 1 < N) { rowptr[i0 + 1] = p1; cursor[i0 + 1] = p1; }
            if (i0 + 2 < N) { rowptr[i0 + 2] = p2; cursor[i0 + 2] = p2; }
            if (i0 + 3 < N) { rowptr[i0 + 3] = p3; cursor[i0 + 3] = p3; }
        }
        __syncthreads();
        if (t == 0) base_s += wsum[15];
        __syncthreads();
    }
    if (t == 0) rowptr[N] = base_s;
}

// Scatter edge (src,dst) into CSR order.
__global__ void scatter_kernel(const int* __restrict__ ei, int E, int E2,
                               int* __restrict__ cursor,
                               int* __restrict__ src_csr, int* __restrict__ dst_csr) {
    int i = blockIdx.x * blockDim.x + threadIdx.x;
    if (i >= E2) return;
    int src, dst;
    if (i < E) { src = ei[i]; dst = ei[E + i]; }
    else       { src = i - E; dst = src; }
    int pos = atomicAdd(cursor + dst, 1);
    src_csr[pos] = src;
    dst_csr[pos] = dst;
}

// ---------------------------------------------------------------------------
// GEMM: h[N,512](bf16) = xin[N,K](fp32) @ W[K,512]; BM=32 (round-6 proven).
// Thread t owns adjacent columns (2t, 2t+1): float2 W loads, packed dword
// bf16 stores. u/v staged to LDS; asv/adv epilogue reads LDS only.
// __launch_bounds__(256,2): VGPR cap ~256 — forbid the round-7 spill regime.
template <int K>
__launch_bounds__(256, 2)
__global__ void gemm_kernel(const float* __restrict__ xin, const float* __restrict__ W,
                            unsigned* __restrict__ hout, int N,
                            const float* __restrict__ scale, const float* __restrict__ shift,
                            const float* __restrict__ u, const float* __restrict__ v,
                            float* __restrict__ asv, float* __restrict__ adv) {
    const int BM = 32;
    __shared__ float xs[BM * K];
    __shared__ float us[K * 8];
    __shared__ float vs[K * 8];
    int row0 = blockIdx.x * BM;
    int t = threadIdx.x;
    for (int idx = t; idx < K * 8; idx += 256) { us[idx] = u[idx]; vs[idx] = v[idx]; }
    for (int idx = t; idx < BM * K; idx += 256) {
        int r = row0 + idx / K;
        int f = idx & (K - 1);
        float vv = (r < N) ? xin[(size_t)r * K + f] : 0.f;
        if (scale) vv = vv * scale[f] + shift[f];
        xs[idx] = vv;
    }
    __syncthreads();
    int c0 = 2 * t;
    float acc0[BM], acc1[BM];
#pragma unroll
    for (int r = 0; r < BM; r++) { acc0[r] = 0.f; acc1[r] = 0.f; }
    for (int k = 0; k < K; k++) {
        float2 w = *(const float2*)(W + (size_t)k * HC + c0);
#pragma unroll
        for (int r = 0; r < BM; r++) {
            float a = xs[r * K + k];
            acc0[r] += a * w.x;
            acc1[r] += a * w.y;
        }
    }
#pragma unroll
    for (int r = 0; r < BM; r++) {
        int rr = row0 + r;
        if (rr < N) hout[(size_t)rr * (HC / 2) + t] = packbf2(acc0[r], acc1[r]);
    }
    // asv/adv epilogue: 256 threads, each one (row, head) K-dot from LDS.
    {
        int r = t >> 3, hh = t & 7;
        int rr = row0 + r;
        if (rr < N) {
            float su = 0.f, sv = 0.f;
            for (int k = 0; k < K; k++) {
                float xv = xs[r * K + k];
                su += xv * us[k * 8 + hh];
                sv += xv * vs[k * 8 + hh];
            }
            asv[(size_t)rr * 8 + hh] = su;
            adv[(size_t)rr * 8 + hh] = sv;
        }
    }
}

// ---------------------------------------------------------------------------
// Unnormalized attention weights in CSR order: alpha[j][h] = exp(lrelu(...)).
__global__ void alpha_kernel(const int* __restrict__ src_csr, const int* __restrict__ dst_csr,
                             const float* __restrict__ asv, const float* __restrict__ adv,
                             float* __restrict__ alpha_csr, int E2) {
    int tid = blockIdx.x * blockDim.x + threadIdx.x;
    if (tid >= E2 * 8) return;
    int j = tid >> 3, h = tid & 7;
    int s = src_csr[j], d = dst_csr[j];
    float e = lrelu(asv[(size_t)s * 8 + h] + adv[(size_t)d * 8 + h]);
    alpha_csr[tid] = __expf(e);
}

// ---------------------------------------------------------------------------
// Aggregation: one WAVE per dst node, PURE gather+FMA loop, 4-edge unroll.
__global__ void agg_kernel(const int* __restrict__ rp, const int* __restrict__ src_csr,
                           const float* __restrict__ alpha_csr,
                           const ushort* __restrict__ hbuf, const float* __restrict__ bias,
                           float* __restrict__ xout, int N, int dorelu) {
    int gw = (blockIdx.x * blockDim.x + threadIdx.x) >> 6;  // node id
    int lane = threadIdx.x & 63;
    if (gw >= N) return;
    int head = lane >> 3;
    size_t lofs = 8 * (size_t)lane;
    int jb = rp[gw], je = rp[gw + 1];
    float acc[8];
#pragma unroll
    for (int r = 0; r < 8; r++) acc[r] = 0.f;
    float den = 0.f;
    int j = jb;
    for (; j + 4 <= je; j += 4) {
        int s0 = src_csr[j],     s1 = src_csr[j + 1];
        int s2 = src_csr[j + 2], s3 = src_csr[j + 3];
        float w0 = alpha_csr[(size_t)j * 8 + head];
        float w1 = alpha_csr[(size_t)(j + 1) * 8 + head];
        float w2 = alpha_csr[(size_t)(j + 2) * 8 + head];
        float w3 = alpha_csr[(size_t)(j + 3) * 8 + head];
        uint4 p0 = *(const uint4*)(hbuf + (size_t)s0 * HC + lofs);
        uint4 p1 = *(const uint4*)(hbuf + (size_t)s1 * HC + lofs);
        uint4 p2 = *(const uint4*)(hbuf + (size_t)s2 * HC + lofs);
        uint4 p3 = *(const uint4*)(hbuf + (size_t)s3 * HC + lofs);
        den += (w0 + w1) + (w2 + w3);
        acc[0] += w0 * bf2f_lo(p0.x); acc[1] += w0 * bf2f_hi(p0.x);
        acc[2] += w0 * bf2f_lo(p0.y); acc[3] += w0 * bf2f_hi(p0.y);
        acc[4] += w0 * bf2f_lo(p0.z); acc[5] += w0 * bf2f_hi(p0.z);
        acc[6] += w0 * bf2f_lo(p0.w); acc[7] += w0 * bf2f_hi(p0.w);
        acc[0] += w1 * bf2f_lo(p1.x); acc[1] += w1 * bf2f_hi(p1.x);
        acc[2] += w1 * bf2f_lo(p1.y); acc[3] += w1 * bf2f_hi(p1.y);
        acc[4] += w1 * bf2f_lo(p1.z); acc[5] += w1 * bf2f_hi(p1.z);
        acc[6] += w1 * bf2f_lo(p1.w); acc[7] += w1 * bf2f_hi(p1.w);
        acc[0] += w2 * bf2f_lo(p2.x); acc[1] += w2 * bf2f_hi(p2.x);
        acc[2] += w2 * bf2f_lo(p2.y); acc[3] += w2 * bf2f_hi(p2.y);
        acc[4] += w2 * bf2f_lo(p2.z); acc[5] += w2 * bf2f_hi(p2.z);
        acc[6] += w2 * bf2f_lo(p2.w); acc[7] += w2 * bf2f_hi(p2.w);
        acc[0] += w3 * bf2f_lo(p3.x); acc[1] += w3 * bf2f_hi(p3.x);
        acc[2] += w3 * bf2f_lo(p3.y); acc[3] += w3 * bf2f_hi(p3.y);
        acc[4] += w3 * bf2f_lo(p3.z); acc[5] += w3 * bf2f_hi(p3.z);
        acc[6] += w3 * bf2f_lo(p3.w); acc[7] += w3 * bf2f_hi(p3.w);
    }
    for (; j < je; j++) {
        int s0 = src_csr[j];
        float w0 = alpha_csr[(size_t)j * 8 + head];
        uint4 p0 = *(const uint4*)(hbuf + (size_t)s0 * HC + lofs);
        den += w0;
        acc[0] += w0 * bf2f_lo(p0.x); acc[1] += w0 * bf2f_hi(p0.x);
        acc[2] += w0 * bf2f_lo(p0.y); acc[3] += w0 * bf2f_hi(p0.y);
        acc[4] += w0 * bf2f_lo(p0.z); acc[5] += w0 * bf2f_hi(p0.z);
        acc[6] += w0 * bf2f_lo(p0.w); acc[7] += w0 * bf2f_hi(p0.w);
    }
    float inv = 1.f / (den + 1e-16f);
#pragma unroll
    for (int r = 0; r < 8; r++) {
        acc[r] *= inv;
        acc[r] += __shfl_xor(acc[r], 8);
        acc[r] += __shfl_xor(acc[r], 16);
        acc[r] += __shfl_xor(acc[r], 32);
    }
    if (lane < 8) {
        const float4* b4 = (const float4*)(bias + 8 * lane);
        float4 bv0 = b4[0], bv1 = b4[1];
        float4 o0, o1;
        o0.x = acc[0] * 0.125f + bv0.x;
        o0.y = acc[1] * 0.125f + bv0.y;
        o0.z = acc[2] * 0.125f + bv0.z;
        o0.w = acc[3] * 0.125f + bv0.w;
        o1.x = acc[4] * 0.125f + bv1.x;
        o1.y = acc[5] * 0.125f + bv1.y;
        o1.z = acc[6] * 0.125f + bv1.z;
        o1.w = acc[7] * 0.125f + bv1.w;
        if (dorelu) {
            o0.x = fmaxf(o0.x, 0.f); o0.y = fmaxf(o0.y, 0.f);
            o0.z = fmaxf(o0.z, 0.f); o0.w = fmaxf(o0.w, 0.f);
            o1.x = fmaxf(o1.x, 0.f); o1.y = fmaxf(o1.y, 0.f);
            o1.z = fmaxf(o1.z, 0.f); o1.w = fmaxf(o1.w, 0.f);
        }
        float4* op = (float4*)(xout + (size_t)gw * CH + 8 * lane);
        op[0] = o0;
        op[1] = o1;
    }
}

// ---------------------------------------------------------------------------
// Pool: batch sorted -> run-local accumulation, atomic flush per boundary.
__global__ void pool_kernel(const float* __restrict__ x, const int* __restrict__ batch,
                            float* __restrict__ pools, float* __restrict__ pcnt,
                            int N, int chunk) {
    int c  = threadIdx.x & 63;
    int nl = threadIdx.x >> 6;   // 0..3
    int n0 = blockIdx.x * chunk;
    int n1 = min(n0 + chunk, N);
    float acc = 0.f, cnt = 0.f;
    int curg = -1;
    for (int n = n0 + nl; n < n1; n += 4) {
        int g = batch[n];
        if (g != curg) {
            if (curg >= 0) {
                atomicAdd(pools + (size_t)curg * CH + c, acc);
                if (c == 0) atomicAdd(pcnt + curg, cnt);
            }
            curg = g; acc = 0.f; cnt = 0.f;
        }
        acc += x[(size_t)n * CH + c];
        cnt += 1.f;
    }
    if (curg >= 0) {
        atomicAdd(pools + (size_t)curg * CH + c, acc);
        if (c == 0) atomicAdd(pcnt + curg, cnt);
    }
}

__global__ void final_kernel(const float* __restrict__ pools, const float* __restrict__ pcnt,
                             const float* __restrict__ linW, const float* __restrict__ linb,
                             float* __restrict__ out) {
    int t = threadIdx.x;
    if (t >= NGR * 2) return;
    int g = t >> 1, k = t & 1;
    float inv = 1.f / fmaxf(pcnt[g], 1.f);
    float acc = 0.f;
#pragma unroll
    for (int c = 0; c < CH; c++)
        acc += pools[(size_t)g * CH + c] * inv * linW[c * 2 + k];
    out[g * 2 + k] = acc + linb[k];
}

// ---------------------------------------------------------------------------
extern "C" void kernel_launch(void* const* d_in, const int* in_sizes, int n_in,
                              void* d_out, int out_size, void* d_ws, size_t ws_size,
                              hipStream_t stream) {
    const float* x      = (const float*)d_in[0];
    const int*   ei     = (const int*)d_in[1];
    const int*   batch  = (const int*)d_in[3];
    const float* gamma  = (const float*)d_in[4];
    const float* beta   = (const float*)d_in[5];
    const float* W1     = (const float*)d_in[6];
    const float* a1s    = (const float*)d_in[7];
    const float* a1d    = (const float*)d_in[8];
    const float* b1     = (const float*)d_in[9];
    const float* W2     = (const float*)d_in[10];
    const float* a2s    = (const float*)d_in[11];
    const float* a2d    = (const float*)d_in[12];
    const float* b2     = (const float*)d_in[13];
    const float* W3     = (const float*)d_in[14];
    const float* a3s    = (const float*)d_in[15];
    const float* a3d    = (const float*)d_in[16];
    const float* b3     = (const float*)d_in[17];
    const float* linW   = (const float*)d_in[18];
    const float* linb   = (const float*)d_in[19];
    float* out = (float*)d_out;

    const int N  = in_sizes[0] / 16;
    const int E  = in_sizes[1] / 2;
    const int E2 = E + N;

    // Workspace layout (256B aligned slices)
    char* p = (char*)d_ws;
    size_t off = 0;
    auto alloc = [&](size_t bytes) {
        void* r = p + off;
        off += (bytes + 255) & ~(size_t)255;
        return r;
    };
    unsigned* hbuf   = (unsigned*)alloc((size_t)N * HC * 2);   // bf16 x2 packed
    float* xa        = (float*)alloc((size_t)N * CH * 4);
    float* xb        = (float*)alloc((size_t)N * CH * 4);
    float* asv       = (float*)alloc((size_t)N * HEADS * 4);
    float* adv       = (float*)alloc((size_t)N * HEADS * 4);
    float* alpha_csr = (float*)alloc((size_t)E2 * HEADS * 4);
    float* stats     = (float*)alloc(64 * 4);
    float* partials  = (float*)alloc((size_t)BNB * 32 * 4);
    float* uv        = (float*)alloc(2304 * 4);
    float* pools     = (float*)alloc((size_t)NGR * CH * 4);
    float* pcnt      = (float*)alloc(NGR * 4);
    int*   rowptr    = (int*)alloc((size_t)(N + 1) * 4);
    int*   cursor    = (int*)alloc((size_t)N * 4);
    int*   counts    = (int*)alloc((size_t)N * 4);
    int*   src_csr   = (int*)alloc((size_t)E2 * 4);
    int*   dst_csr   = (int*)alloc((size_t)E2 * 4);
    (void)ws_size;

    const int TB = 256;
    int gE2 = (E2 + TB - 1) / TB;
    int gEH = (E2 * 8 + TB - 1) / TB;
    int gGm = (N + 31) / 32;               // BM=32
    int gWv = (N * 64 + TB - 1) / TB;      // one wave per node
    const int PCHUNK = 256;
    int gPool = (N + PCHUNK - 1) / PCHUNK;
    int bnChunk = (N + BNB - 1) / BNB;

    const ushort* hb = (const ushort*)hbuf;

    // zero-init accumulators
    hipMemsetAsync(counts, 0, (size_t)N * 4, stream);
    hipMemsetAsync(pools, 0, (size_t)NGR * CH * 4, stream);
    hipMemsetAsync(pcnt, 0, NGR * 4, stream);

    // BN statistics (two-stage deterministic reduction) + u/v precompute
    bn_stats_kernel<<<BNB, TB, 0, stream>>>(x, partials, N, bnChunk);
    bn_finalize_kernel<<<1, 64, 0, stream>>>(partials, stats, gamma, beta, N, BNB);
    uv_kernel<<<3, 512, 0, stream>>>(W1, a1s, a1d, W2, a2s, a2d, W3, a3s, a3d, uv);

    // CSR over dst
    count_kernel<<<gE2, TB, 0, stream>>>(ei, E, E2, counts);
    scan_kernel<<<1, 1024, 0, stream>>>(counts, rowptr, cursor, N);
    scatter_kernel<<<gE2, TB, 0, stream>>>(ei, E, E2, cursor, src_csr, dst_csr);

    // ---- Layer 1 (BN fused into GEMM staging; asv/adv fused epilogue) ----
    gemm_kernel<16><<<gGm, TB, 0, stream>>>(x, W1, hbuf, N, stats + 32, stats + 48,
                                            uv + 0, uv + 128, asv, adv);
    alpha_kernel<<<gEH, TB, 0, stream>>>(src_csr, dst_csr, asv, adv, alpha_csr, E2);
    agg_kernel<<<gWv, TB, 0, stream>>>(rowptr, src_csr, alpha_csr, hb, b1, xa, N, 1);

    // ---- Layer 2 ----
    gemm_kernel<64><<<gGm, TB, 0, stream>>>(xa, W2, hbuf, N, nullptr, nullptr,
                                            uv + 256, uv + 768, asv, adv);
    alpha_kernel<<<gEH, TB, 0, stream>>>(src_csr, dst_csr, asv, adv, alpha_csr, E2);
    agg_kernel<<<gWv, TB, 0, stream>>>(rowptr, src_csr, alpha_csr, hb, b2, xb, N, 1);

    // ---- Layer 3 ----
    gemm_kernel<64><<<gGm, TB, 0, stream>>>(xb, W3, hbuf, N, nullptr, nullptr,
                                            uv + 1280, uv + 1792, asv, adv);
    alpha_kernel<<<gEH, TB, 0, stream>>>(src_csr, dst_csr, asv, adv, alpha_csr, E2);
    agg_kernel<<<gWv, TB, 0, stream>>>(rowptr, src_csr, alpha_csr, hb, b3, xa, N, 0);

    // ---- Pool + final linear ----
    pool_kernel<<<gPool, TB, 0, stream>>>(xa, batch, pools, pcnt, N, PCHUNK);
    final_kernel<<<1, 128, 0, stream>>>(pools, pcnt, linW, linb, out);
}

// Round 9
// 543.337 us; speedup vs baseline: 1.2133x; 1.0359x over previous
//
#include <hip/hip_runtime.h>
#include <hip/hip_bf16.h>

// Problem constants
#define HEADS 8
#define CH    64
#define HC    512   // HEADS*CH
#define NGR   64
#define NEGS  0.2f
#define BNB   60    // bn_stats blocks

__device__ __forceinline__ float lrelu(float v) {
    return (v > 0.f) ? v : NEGS * v;
}

// bf16 (as ushort) -> fp32
__device__ __forceinline__ float bf2f_lo(unsigned u) { return __uint_as_float(u << 16); }
__device__ __forceinline__ float bf2f_hi(unsigned u) { return __uint_as_float(u & 0xffff0000u); }

// fp32 -> bf16 bits, round-to-nearest-even (finite inputs)
__device__ __forceinline__ unsigned bf16bits(float f) {
    unsigned u = __float_as_uint(f);
    return (u + 0x7fffu + ((u >> 16) & 1u)) >> 16;
}
__device__ __forceinline__ unsigned packbf2(float a, float b) {
    return bf16bits(a) | (bf16bits(b) << 16);
}

// ---------------------------------------------------------------------------
// BN stats stage 1: per-block partial sum/sumsq over 16 features, NO atomics.
__global__ void bn_stats_kernel(const float* __restrict__ x, float* __restrict__ partials,
                                int N, int chunk) {
    int n0 = blockIdx.x * chunk;
    int n1 = min(n0 + chunk, N);
    float s[16], q[16];
#pragma unroll
    for (int i = 0; i < 16; i++) { s[i] = 0.f; q[i] = 0.f; }
    for (int r = n0 + threadIdx.x; r < n1; r += 256) {
        const float4* xr = (const float4*)(x + (size_t)r * 16);
#pragma unroll
        for (int i = 0; i < 4; i++) {
            float4 v = xr[i];
            s[4*i+0] += v.x; q[4*i+0] += v.x * v.x;
            s[4*i+1] += v.y; q[4*i+1] += v.y * v.y;
            s[4*i+2] += v.z; q[4*i+2] += v.z * v.z;
            s[4*i+3] += v.w; q[4*i+3] += v.w * v.w;
        }
    }
#pragma unroll
    for (int k = 0; k < 16; k++) {
#pragma unroll
        for (int off = 32; off; off >>= 1) {
            s[k] += __shfl_down(s[k], off);
            q[k] += __shfl_down(q[k], off);
        }
    }
    __shared__ float lds[4][32];
    int lane = threadIdx.x & 63, wid = threadIdx.x >> 6;
    if (lane == 0) {
#pragma unroll
        for (int k = 0; k < 16; k++) { lds[wid][k] = s[k]; lds[wid][16 + k] = q[k]; }
    }
    __syncthreads();
    int t = threadIdx.x;
    if (t < 32) {
        float v = lds[0][t] + lds[1][t] + lds[2][t] + lds[3][t];
        partials[(size_t)blockIdx.x * 32 + t] = v;
    }
}

// BN stage 2: stats[32..47]=scale, stats[48..63]=shift.
__global__ void bn_finalize_kernel(const float* __restrict__ partials, float* __restrict__ stats,
                                   const float* __restrict__ gamma,
                                   const float* __restrict__ beta, int N, int nblk) {
    __shared__ float sums[32];
    int t = threadIdx.x;
    if (t < 32) {
        float v = 0.f;
        for (int b = 0; b < nblk; b++) v += partials[(size_t)b * 32 + t];
        sums[t] = v;
    }
    __syncthreads();
    if (t < 16) {
        float invn = 1.f / (float)N;
        float mean = sums[t] * invn;
        float var  = sums[16 + t] * invn - mean * mean;
        float sc   = gamma[t] * rsqrtf(var + 1e-5f);
        stats[32 + t] = sc;
        stats[48 + t] = beta[t] - mean * sc;
    }
}

// ---------------------------------------------------------------------------
// u/v precompute: u[k,h] = sum_c W[k, h*64+c] * a_src[h,c]  (asv = x.u exactly)
// uv layout: [0]=u1(16x8) [128]=v1 [256]=u2(64x8) [768]=v2 [1280]=u3 [1792]=v3
__global__ void uv_kernel(const float* __restrict__ W1, const float* __restrict__ a1s,
                          const float* __restrict__ a1d,
                          const float* __restrict__ W2, const float* __restrict__ a2s,
                          const float* __restrict__ a2d,
                          const float* __restrict__ W3, const float* __restrict__ a3s,
                          const float* __restrict__ a3d,
                          float* __restrict__ uv) {
    int layer = blockIdx.x;
    const float* W  = (layer == 0) ? W1  : (layer == 1) ? W2  : W3;
    const float* as = (layer == 0) ? a1s : (layer == 1) ? a2s : a3s;
    const float* ad = (layer == 0) ? a1d : (layer == 1) ? a2d : a3d;
    int K = (layer == 0) ? 16 : 64;
    int uofs = (layer == 0) ? 0 : (layer == 1) ? 256 : 1280;
    int t = threadIdx.x;
    if (t >= K * 8) return;
    int k = t >> 3, h = t & 7;
    const float* wr = W + (size_t)k * HC + h * CH;
    const float* sr = as + h * CH;
    const float* dr = ad + h * CH;
    float su = 0.f, sv = 0.f;
#pragma unroll 8
    for (int c = 0; c < CH; c++) { su += wr[c] * sr[c]; sv += wr[c] * dr[c]; }
    uv[uofs + k * 8 + h] = su;
    uv[uofs + K * 8 + k * 8 + h] = sv;
}

// ---------------------------------------------------------------------------
// CSR build over dst (edges + self loops). E2 = E + N.
__global__ void count_kernel(const int* __restrict__ ei, int E, int E2,
                             int* __restrict__ counts) {
    int i = blockIdx.x * blockDim.x + threadIdx.x;
    if (i >= E2) return;
    int dst = (i < E) ? ei[E + i] : (i - E);
    atomicAdd(counts + dst, 1);
}

// Single-block scan, 4 elems/thread (int4).
__global__ void scan_kernel(const int* __restrict__ counts, int* __restrict__ rowptr,
                            int* __restrict__ cursor, int N) {
    __shared__ int wsum[16];
    __shared__ int base_s;
    int t = threadIdx.x;
    int lane = t & 63, wid = t >> 6;
    if (t == 0) base_s = 0;
    __syncthreads();
    for (int start = 0; start < N; start += 4096) {
        int i0 = start + t * 4;
        int e0 = 0, e1 = 0, e2 = 0, e3 = 0;
        if (i0 + 3 < N) {
            const int4 c4 = *(const int4*)(counts + i0);
            e0 = c4.x; e1 = c4.y; e2 = c4.z; e3 = c4.w;
        } else {
            if (i0 + 0 < N) e0 = counts[i0 + 0];
            if (i0 + 1 < N) e1 = counts[i0 + 1];
            if (i0 + 2 < N) e2 = counts[i0 + 2];
            if (i0 + 3 < N) e3 = counts[i0 + 3];
        }
        int tot = e0 + e1 + e2 + e3;
        int v = tot;
#pragma unroll
        for (int off = 1; off < 64; off <<= 1) {
            int u = __shfl_up(v, off);
            if (lane >= off) v += u;
        }
        if (lane == 63) wsum[wid] = v;
        __syncthreads();
        if (t < 16) {
            int w = wsum[t];
#pragma unroll
            for (int off = 1; off < 16; off <<= 1) {
                int u = __shfl_up(w, off);
                if (t >= off) w += u;
            }
            wsum[t] = w;
        }
        __syncthreads();
        int excl = base_s + (v - tot) + (wid ? wsum[wid - 1] : 0);
        int p0 = excl, p1 = p0 + e0, p2 = p1 + e1, p3 = p2 + e2;
        if (i0 + 3 < N) {
            *(int4*)(rowptr + i0) = make_int4(p0, p1, p2, p3);
            *(int4*)(cursor + i0) = make_int4(p0, p1, p2, p3);
        } else {
            if (i0 + 0 < N) { rowptr[i0 + 0] = p0; cursor[i0 + 0] = p0; }
            if (i0 + 1 < N) { rowptr[i0 + 1] = p1; cursor[i0 + 1] = p1; }
            if (i0 + 2 < N) { rowptr[i0 + 2] = p2; cursor[i0 + 2] = p2; }
            if (i0 + 3 < N) { rowptr[i0 + 3] = p3; cursor[i0 + 3] = p3; }
        }
        __syncthreads();
        if (t == 0) base_s += wsum[15];
        __syncthreads();
    }
    if (t == 0) rowptr[N] = base_s;
}

// Scatter edge (src,dst) into CSR order (src only; dst implied by row).
__global__ void scatter_kernel(const int* __restrict__ ei, int E, int E2,
                               int* __restrict__ cursor, int* __restrict__ src_csr) {
    int i = blockIdx.x * blockDim.x + threadIdx.x;
    if (i >= E2) return;
    int src, dst;
    if (i < E) { src = ei[i]; dst = ei[E + i]; }
    else       { src = i - E; dst = src; }
    int pos = atomicAdd(cursor + dst, 1);
    src_csr[pos] = src;
}

// ---------------------------------------------------------------------------
// GEMM: h[N,512](bf16) = xin[N,K](fp32) @ W[K,512]; BM=32; packed dword bf16
// stores; asv/adv fused epilogue from LDS. launch_bounds forbids spills.
template <int K>
__launch_bounds__(256, 2)
__global__ void gemm_kernel(const float* __restrict__ xin, const float* __restrict__ W,
                            unsigned* __restrict__ hout, int N,
                            const float* __restrict__ scale, const float* __restrict__ shift,
                            const float* __restrict__ u, const float* __restrict__ v,
                            float* __restrict__ asv, float* __restrict__ adv) {
    const int BM = 32;
    __shared__ float xs[BM * K];
    __shared__ float us[K * 8];
    __shared__ float vs[K * 8];
    int row0 = blockIdx.x * BM;
    int t = threadIdx.x;
    for (int idx = t; idx < K * 8; idx += 256) { us[idx] = u[idx]; vs[idx] = v[idx]; }
    for (int idx = t; idx < BM * K; idx += 256) {
        int r = row0 + idx / K;
        int f = idx & (K - 1);
        float vv = (r < N) ? xin[(size_t)r * K + f] : 0.f;
        if (scale) vv = vv * scale[f] + shift[f];
        xs[idx] = vv;
    }
    __syncthreads();
    int c0 = 2 * t;
    float acc0[BM], acc1[BM];
#pragma unroll
    for (int r = 0; r < BM; r++) { acc0[r] = 0.f; acc1[r] = 0.f; }
    for (int k = 0; k < K; k++) {
        float2 w = *(const float2*)(W + (size_t)k * HC + c0);
#pragma unroll
        for (int r = 0; r < BM; r++) {
            float a = xs[r * K + k];
            acc0[r] += a * w.x;
            acc1[r] += a * w.y;
        }
    }
#pragma unroll
    for (int r = 0; r < BM; r++) {
        int rr = row0 + r;
        if (rr < N) hout[(size_t)rr * (HC / 2) + t] = packbf2(acc0[r], acc1[r]);
    }
    // asv/adv epilogue: 256 threads, each one (row, head) K-dot from LDS.
    {
        int r = t >> 3, hh = t & 7;
        int rr = row0 + r;
        if (rr < N) {
            float su = 0.f, sv = 0.f;
            for (int k = 0; k < K; k++) {
                float xv = xs[r * K + k];
                su += xv * us[k * 8 + hh];
                sv += xv * vs[k * 8 + hh];
            }
            asv[(size_t)rr * 8 + hh] = su;
            adv[(size_t)rr * 8 + hh] = sv;
        }
    }
}

// ---------------------------------------------------------------------------
// Fused softmax+aggregation: one WAVE per dst node. Lane l handles head l>>3,
// channels 8(l&7)..+7 via one uint4 (8 bf16) load per edge. Attention weight
// w = exp(lrelu(asv[s][h] + adv[dst][h])) computed inline (alpha kernel
// eliminated); shift-free exp is valid since normalization cancels it.
__global__ void agg_kernel(const int* __restrict__ rp, const int* __restrict__ src_csr,
                           const float* __restrict__ asv, const float* __restrict__ adv,
                           const ushort* __restrict__ hbuf, const float* __restrict__ bias,
                           float* __restrict__ xout, int N, int dorelu) {
    int gw = (blockIdx.x * blockDim.x + threadIdx.x) >> 6;  // node id
    int lane = threadIdx.x & 63;
    if (gw >= N) return;
    int head = lane >> 3;
    size_t lofs = 8 * (size_t)lane;
    int jb = rp[gw], je = rp[gw + 1];
    float ad = adv[(size_t)gw * 8 + head];   // per-wave constant (per head group)
    float acc[8];
#pragma unroll
    for (int r = 0; r < 8; r++) acc[r] = 0.f;
    float den = 0.f;
    int j = jb;
    for (; j + 4 <= je; j += 4) {
        int s0 = src_csr[j],     s1 = src_csr[j + 1];
        int s2 = src_csr[j + 2], s3 = src_csr[j + 3];
        float w0 = __expf(lrelu(asv[(size_t)s0 * 8 + head] + ad));
        float w1 = __expf(lrelu(asv[(size_t)s1 * 8 + head] + ad));
        float w2 = __expf(lrelu(asv[(size_t)s2 * 8 + head] + ad));
        float w3 = __expf(lrelu(asv[(size_t)s3 * 8 + head] + ad));
        uint4 p0 = *(const uint4*)(hbuf + (size_t)s0 * HC + lofs);
        uint4 p1 = *(const uint4*)(hbuf + (size_t)s1 * HC + lofs);
        uint4 p2 = *(const uint4*)(hbuf + (size_t)s2 * HC + lofs);
        uint4 p3 = *(const uint4*)(hbuf + (size_t)s3 * HC + lofs);
        den += (w0 + w1) + (w2 + w3);
        acc[0] += w0 * bf2f_lo(p0.x); acc[1] += w0 * bf2f_hi(p0.x);
        acc[2] += w0 * bf2f_lo(p0.y); acc[3] += w0 * bf2f_hi(p0.y);
        acc[4] += w0 * bf2f_lo(p0.z); acc[5] += w0 * bf2f_hi(p0.z);
        acc[6] += w0 * bf2f_lo(p0.w); acc[7] += w0 * bf2f_hi(p0.w);
        acc[0] += w1 * bf2f_lo(p1.x); acc[1] += w1 * bf2f_hi(p1.x);
        acc[2] += w1 * bf2f_lo(p1.y); acc[3] += w1 * bf2f_hi(p1.y);
        acc[4] += w1 * bf2f_lo(p1.z); acc[5] += w1 * bf2f_hi(p1.z);
        acc[6] += w1 * bf2f_lo(p1.w); acc[7] += w1 * bf2f_hi(p1.w);
        acc[0] += w2 * bf2f_lo(p2.x); acc[1] += w2 * bf2f_hi(p2.x);
        acc[2] += w2 * bf2f_lo(p2.y); acc[3] += w2 * bf2f_hi(p2.y);
        acc[4] += w2 * bf2f_lo(p2.z); acc[5] += w2 * bf2f_hi(p2.z);
        acc[6] += w2 * bf2f_lo(p2.w); acc[7] += w2 * bf2f_hi(p2.w);
        acc[0] += w3 * bf2f_lo(p3.x); acc[1] += w3 * bf2f_hi(p3.x);
        acc[2] += w3 * bf2f_lo(p3.y); acc[3] += w3 * bf2f_hi(p3.y);
        acc[4] += w3 * bf2f_lo(p3.z); acc[5] += w3 * bf2f_hi(p3.z);
        acc[6] += w3 * bf2f_lo(p3.w); acc[7] += w3 * bf2f_hi(p3.w);
    }
    for (; j < je; j++) {
        int s0 = src_csr[j];
        float w0 = __expf(lrelu(asv[(size_t)s0 * 8 + head] + ad));
        uint4 p0 = *(const uint4*)(hbuf + (size_t)s0 * HC + lofs);
        den += w0;
        acc[0] += w0 * bf2f_lo(p0.x); acc[1] += w0 * bf2f_hi(p0.x);
        acc[2] += w0 * bf2f_lo(p0.y); acc[3] += w0 * bf2f_hi(p0.y);
        acc[4] += w0 * bf2f_lo(p0.z); acc[5] += w0 * bf2f_hi(p0.z);
        acc[6] += w0 * bf2f_lo(p0.w); acc[7] += w0 * bf2f_hi(p0.w);
    }
    float inv = 1.f / (den + 1e-16f);
#pragma unroll
    for (int r = 0; r < 8; r++) {
        acc[r] *= inv;
        acc[r] += __shfl_xor(acc[r], 8);
        acc[r] += __shfl_xor(acc[r], 16);
        acc[r] += __shfl_xor(acc[r], 32);
    }
    if (lane < 8) {
        const float4* b4 = (const float4*)(bias + 8 * lane);
        float4 bv0 = b4[0], bv1 = b4[1];
        float4 o0, o1;
        o0.x = acc[0] * 0.125f + bv0.x;
        o0.y = acc[1] * 0.125f + bv0.y;
        o0.z = acc[2] * 0.125f + bv0.z;
        o0.w = acc[3] * 0.125f + bv0.w;
        o1.x = acc[4] * 0.125f + bv1.x;
        o1.y = acc[5] * 0.125f + bv1.y;
        o1.z = acc[6] * 0.125f + bv1.z;
        o1.w = acc[7] * 0.125f + bv1.w;
        if (dorelu) {
            o0.x = fmaxf(o0.x, 0.f); o0.y = fmaxf(o0.y, 0.f);
            o0.z = fmaxf(o0.z, 0.f); o0.w = fmaxf(o0.w, 0.f);
            o1.x = fmaxf(o1.x, 0.f); o1.y = fmaxf(o1.y, 0.f);
            o1.z = fmaxf(o1.z, 0.f); o1.w = fmaxf(o1.w, 0.f);
        }
        float4* op = (float4*)(xout + (size_t)gw * CH + 8 * lane);
        op[0] = o0;
        op[1] = o1;
    }
}

// ---------------------------------------------------------------------------
// Fused mean-pool + linear: one block per graph. batch is sorted; block finds
// its [lo,hi) node range by binary search, reduces deterministically in LDS.
__global__ void poolfinal_kernel(const float* __restrict__ x, const int* __restrict__ batch,
                                 const float* __restrict__ linW, const float* __restrict__ linb,
                                 float* __restrict__ out, int N) {
    int g = blockIdx.x;
    // lower_bound(batch, g) and lower_bound(batch, g+1)
    int lo = 0, hi = N;
    while (lo < hi) { int m = (lo + hi) >> 1; if (batch[m] < g) lo = m + 1; else hi = m; }
    int lo2 = lo, hi2 = N;
    while (lo2 < hi2) { int m = (lo2 + hi2) >> 1; if (batch[m] < g + 1) lo2 = m + 1; else hi2 = m; }
    int n0 = lo, n1 = lo2;
    int c  = threadIdx.x & 63;
    int nl = threadIdx.x >> 6;   // 0..3
    float acc = 0.f;
    for (int n = n0 + nl; n < n1; n += 4)
        acc += x[(size_t)n * CH + c];
    __shared__ float lds[4][64];
    lds[nl][c] = acc;
    __syncthreads();
    __shared__ float pooled[64];
    if (threadIdx.x < 64) {
        float cnt = (float)max(n1 - n0, 1);
        pooled[threadIdx.x] = (lds[0][threadIdx.x] + lds[1][threadIdx.x] +
                               lds[2][threadIdx.x] + lds[3][threadIdx.x]) / cnt;
    }
    __syncthreads();
    if (threadIdx.x < 2) {
        int k = threadIdx.x;
        float s = 0.f;
#pragma unroll
        for (int cc = 0; cc < CH; cc++) s += pooled[cc] * linW[cc * 2 + k];
        out[g * 2 + k] = s + linb[k];
    }
}

// ---------------------------------------------------------------------------
extern "C" void kernel_launch(void* const* d_in, const int* in_sizes, int n_in,
                              void* d_out, int out_size, void* d_ws, size_t ws_size,
                              hipStream_t stream) {
    const float* x      = (const float*)d_in[0];
    const int*   ei     = (const int*)d_in[1];
    const int*   batch  = (const int*)d_in[3];
    const float* gamma  = (const float*)d_in[4];
    const float* beta   = (const float*)d_in[5];
    const float* W1     = (const float*)d_in[6];
    const float* a1s    = (const float*)d_in[7];
    const float* a1d    = (const float*)d_in[8];
    const float* b1     = (const float*)d_in[9];
    const float* W2     = (const float*)d_in[10];
    const float* a2s    = (const float*)d_in[11];
    const float* a2d    = (const float*)d_in[12];
    const float* b2     = (const float*)d_in[13];
    const float* W3     = (const float*)d_in[14];
    const float* a3s    = (const float*)d_in[15];
    const float* a3d    = (const float*)d_in[16];
    const float* b3     = (const float*)d_in[17];
    const float* linW   = (const float*)d_in[18];
    const float* linb   = (const float*)d_in[19];
    float* out = (float*)d_out;

    const int N  = in_sizes[0] / 16;
    const int E  = in_sizes[1] / 2;
    const int E2 = E + N;

    // Workspace layout (256B aligned slices)
    char* p = (char*)d_ws;
    size_t off = 0;
    auto alloc = [&](size_t bytes) {
        void* r = p + off;
        off += (bytes + 255) & ~(size_t)255;
        return r;
    };
    unsigned* hbuf   = (unsigned*)alloc((size_t)N * HC * 2);   // bf16 x2 packed
    float* xa        = (float*)alloc((size_t)N * CH * 4);
    float* xb        = (float*)alloc((size_t)N * CH * 4);
    float* asv       = (float*)alloc((size_t)N * HEADS * 4);
    float* adv       = (float*)alloc((size_t)N * HEADS * 4);
    float* stats     = (float*)alloc(64 * 4);
    float* partials  = (float*)alloc((size_t)BNB * 32 * 4);
    float* uv        = (float*)alloc(2304 * 4);
    int*   rowptr    = (int*)alloc((size_t)(N + 1) * 4);
    int*   cursor    = (int*)alloc((size_t)N * 4);
    int*   counts    = (int*)alloc((size_t)N * 4);
    int*   src_csr   = (int*)alloc((size_t)E2 * 4);
    (void)ws_size;

    const int TB = 256;
    int gE2 = (E2 + TB - 1) / TB;
    int gGm = (N + 31) / 32;               // BM=32
    int gWv = (N * 64 + TB - 1) / TB;      // one wave per node
    int bnChunk = (N + BNB - 1) / BNB;

    const ushort* hb = (const ushort*)hbuf;

    // zero-init accumulators
    hipMemsetAsync(counts, 0, (size_t)N * 4, stream);

    // BN statistics (two-stage deterministic reduction) + u/v precompute
    bn_stats_kernel<<<BNB, TB, 0, stream>>>(x, partials, N, bnChunk);
    bn_finalize_kernel<<<1, 64, 0, stream>>>(partials, stats, gamma, beta, N, BNB);
    uv_kernel<<<3, 512, 0, stream>>>(W1, a1s, a1d, W2, a2s, a2d, W3, a3s, a3d, uv);

    // CSR over dst
    count_kernel<<<gE2, TB, 0, stream>>>(ei, E, E2, counts);
    scan_kernel<<<1, 1024, 0, stream>>>(counts, rowptr, cursor, N);
    scatter_kernel<<<gE2, TB, 0, stream>>>(ei, E, E2, cursor, src_csr);

    // ---- Layer 1 (BN fused into GEMM staging; asv/adv fused epilogue) ----
    gemm_kernel<16><<<gGm, TB, 0, stream>>>(x, W1, hbuf, N, stats + 32, stats + 48,
                                            uv + 0, uv + 128, asv, adv);
    agg_kernel<<<gWv, TB, 0, stream>>>(rowptr, src_csr, asv, adv, hb, b1, xa, N, 1);

    // ---- Layer 2 ----
    gemm_kernel<64><<<gGm, TB, 0, stream>>>(xa, W2, hbuf, N, nullptr, nullptr,
                                            uv + 256, uv + 768, asv, adv);
    agg_kernel<<<gWv, TB, 0, stream>>>(rowptr, src_csr, asv, adv, hb, b2, xb, N, 1);

    // ---- Layer 3 ----
    gemm_kernel<64><<<gGm, TB, 0, stream>>>(xb, W3, hbuf, N, nullptr, nullptr,
                                            uv + 1280, uv + 1792, asv, adv);
    agg_kernel<<<gWv, TB, 0, stream>>>(rowptr, src_csr, asv, adv, hb, b3, xa, N, 0);

    // ---- Fused mean-pool + linear ----
    poolfinal_kernel<<<NGR, TB, 0, stream>>>(xa, batch, linW, linb, out, N);
}